// Round 1
// baseline (2140.851 us; speedup 1.0000x reference)
//
#include <hip/hip_runtime.h>

// HDCProcessor — single-pass decoupled-lookback chunked scan.
//   hdc[b,t,d] = s1*(0.7*s2*s3 + 0.3) in {±1.0, ∓0.4}; 0.3*s1 for t<2.
//   out[t] = U[t]*(1-DEC)/(1-DEC^{t+1}),  U[t] = DEC*U[t-1] + hdc[t].
// One fused kernel: per-tile local scan -> publish aggregate (flag=1) ->
// lookback over predecessors (linear-recurrence combine, weight DEC^32 per
// hop) -> publish inclusive prefix (flag=2) -> seeded emit. Ticket-ordered
// tile assignment guarantees forward progress without co-residency.

#define VOCAB   256
#define D_      4096
#define T_      2048
#define B_      8
#define DEC     0.95f
#define CHUNK   32
#define NCH     (T_/CHUNK)        // 64
#define THREADS 128
#define DGRP    (D_/(THREADS*8))  // 4  (each thread owns 8 consecutive d's)
#define ROWB    (D_/8)            // 512 bytes per packed row
#define BD      (B_*DGRP)         // 32 tiles per chunk-level
#define NTILE   (NCH*BD)          // 2048

__device__ unsigned char g_P1[VOCAB*ROWB];
__device__ unsigned char g_P2[VOCAB*ROWB];  // signs shifted by 1 along D
__device__ unsigned char g_P3[VOCAB*ROWB];  // signs shifted by 2 along D
__device__ float g_invn[T_];                // (1-DEC)/(1-DEC^{t+1})
__device__ float g_S  [B_*NCH*D_];          // local chunk aggregates  (8 MiB)
__device__ float g_Pfx[B_*NCH*D_];          // inclusive prefixes      (8 MiB)
__device__ int   g_flag[NTILE];             // 0=none 1=aggregate 2=prefix
__device__ unsigned g_tick;

__global__ __launch_bounds__(256) void pack_kernel(const float* __restrict__ cb) {
    int gid = blockIdx.x * 256 + threadIdx.x;     // 0 .. VOCAB*ROWB-1
    int r   = gid >> 9;
    int byt = gid & 511;
    const float* row = cb + r * D_;
    unsigned b1 = 0, b2 = 0, b3 = 0;
#pragma unroll
    for (int j = 0; j < 8; ++j) {
        int d = byt * 8 + j;
        unsigned s1 = __float_as_uint(row[d]) >> 31;
        unsigned s2 = __float_as_uint(row[(d - 1) & (D_ - 1)]) >> 31;
        unsigned s3 = __float_as_uint(row[(d - 2) & (D_ - 1)]) >> 31;
        b1 |= s1 << j; b2 |= s2 << j; b3 |= s3 << j;
    }
    g_P1[gid] = (unsigned char)b1;
    g_P2[gid] = (unsigned char)b2;
    g_P3[gid] = (unsigned char)b3;
    if (gid < T_)
        g_invn[gid] = (1.0f - DEC) / (1.0f - powf(DEC, (float)(gid + 1)));
    if (gid < NTILE) g_flag[gid] = 0;             // reset lookback state
    if (gid == 0)    g_tick = 0u;                 // reset ticket counter
}

// Per-(b,d)-step bind value: v = ±1.0 or ∓0.4 (or 0.3*s1 for t<2).
__device__ __forceinline__ void bind_step(unsigned ub1, unsigned n8,
                                          float magp, float magn, float* acc) {
#pragma unroll
    for (int j = 0; j < 8; ++j) {
        float mag    = ((n8 >> j) & 1u) ? magn : magp;
        unsigned sgn = (ub1 << (31 - j)) & 0x80000000u;
        float v      = __uint_as_float(__float_as_uint(mag) ^ sgn);
        acc[j] = fmaf(acc[j], DEC, v);
    }
}

__global__ __launch_bounds__(THREADS) void fused_kernel(const int* __restrict__ idx,
                                                        float* __restrict__ out) {
    __shared__ int   s_vtile;
    __shared__ int   sidx[CHUNK + 2];
    __shared__ float sinv[CHUNK];

    if (threadIdx.x == 0) s_vtile = (int)atomicAdd(&g_tick, 1u);
    __syncthreads();
    const int v   = s_vtile;          // ticket order == schedule order
    const int ch  = v / BD;           // chunk index ascends with ticket
    const int rem = v - ch * BD;
    const int b   = rem >> 2;         // / DGRP
    const int dg  = rem & (DGRP - 1);
    const int t0  = ch * CHUNK;
    const int lo  = (t0 - 2 > 0) ? (t0 - 2) : 0;

    if (threadIdx.x < (unsigned)(t0 + CHUNK - lo))
        sidx[threadIdx.x] = idx[b * T_ + lo + threadIdx.x];
    if (threadIdx.x < CHUNK)
        sinv[threadIdx.x] = g_invn[t0 + threadIdx.x];
    __syncthreads();

    const int    i  = dg * THREADS + threadIdx.x;
    const size_t so = (size_t)(b * NCH + ch) * D_ + (size_t)i * 8;

    // ---- phase 1: local scan, seed 0 ----
    float acc[8];
#pragma unroll
    for (int j = 0; j < 8; ++j) acc[j] = 0.0f;

#pragma unroll 4
    for (int k = 0; k < CHUNK; ++k) {
        int t = t0 + k;
        int r1 = sidx[t - lo];
        unsigned ub1 = g_P1[r1 * ROWB + i];
        unsigned n8 = 0; float magp = 1.0f, magn = -0.4f;
        if (t >= 2) {
            int r2 = sidx[t - 1 - lo], r3 = sidx[t - 2 - lo];
            n8 = (unsigned)(g_P2[r2 * ROWB + i] ^ g_P3[r3 * ROWB + i]);
        } else { magp = 0.3f; magn = 0.3f; }
        bind_step(ub1, n8, magp, magn, acc);
    }

    // publish: ch==0's aggregate IS its inclusive prefix
    {
        float* dst = (ch == 0 ? g_Pfx : g_S) + so;
        ((float4*)dst)[0] = make_float4(acc[0], acc[1], acc[2], acc[3]);
        ((float4*)dst)[1] = make_float4(acc[4], acc[5], acc[6], acc[7]);
    }
    __threadfence();
    __syncthreads();
    if (threadIdx.x == 0)
        __hip_atomic_store(&g_flag[(b * NCH + ch) * DGRP + dg],
                           (ch == 0) ? 2 : 1,
                           __ATOMIC_RELEASE, __HIP_MEMORY_SCOPE_AGENT);

    float dcp = DEC * DEC;            // DEC^32 by repeated squaring
    dcp *= dcp; dcp *= dcp; dcp *= dcp; dcp *= dcp;

    // ---- phase 2: decoupled lookback ----
    float c[8];
#pragma unroll
    for (int j = 0; j < 8; ++j) c[j] = 0.0f;

    if (ch > 0) {
        float w = 1.0f;
        for (int p = ch - 1; p >= 0; --p) {
            int f;
            while ((f = __hip_atomic_load(&g_flag[(b * NCH + p) * DGRP + dg],
                                          __ATOMIC_ACQUIRE,
                                          __HIP_MEMORY_SCOPE_AGENT)) == 0)
                __builtin_amdgcn_s_sleep(1);
            __threadfence();
            const float* src = (f == 2 ? (const float*)g_Pfx : (const float*)g_S)
                               + (size_t)(b * NCH + p) * D_ + (size_t)i * 8;
            float4 a0 = ((const float4*)src)[0];
            float4 a1 = ((const float4*)src)[1];
            c[0] = fmaf(w, a0.x, c[0]); c[1] = fmaf(w, a0.y, c[1]);
            c[2] = fmaf(w, a0.z, c[2]); c[3] = fmaf(w, a0.w, c[3]);
            c[4] = fmaf(w, a1.x, c[4]); c[5] = fmaf(w, a1.y, c[5]);
            c[6] = fmaf(w, a1.z, c[6]); c[7] = fmaf(w, a1.w, c[7]);
            if (f == 2) break;        // per-lane break is fine: math identical
            w *= dcp;
        }
        if (ch != NCH - 1) {          // last chunk has no successors
            float* dst = g_Pfx + so;  // inclusive prefix = acc + dcp * carry
            ((float4*)dst)[0] = make_float4(fmaf(c[0], dcp, acc[0]),
                                            fmaf(c[1], dcp, acc[1]),
                                            fmaf(c[2], dcp, acc[2]),
                                            fmaf(c[3], dcp, acc[3]));
            ((float4*)dst)[1] = make_float4(fmaf(c[4], dcp, acc[4]),
                                            fmaf(c[5], dcp, acc[5]),
                                            fmaf(c[6], dcp, acc[6]),
                                            fmaf(c[7], dcp, acc[7]));
            __threadfence();
            __syncthreads();
            if (threadIdx.x == 0)
                __hip_atomic_store(&g_flag[(b * NCH + ch) * DGRP + dg], 2,
                                   __ATOMIC_RELEASE, __HIP_MEMORY_SCOPE_AGENT);
        }
    }

    // ---- phase 3: seeded emit (L1 warm from phase 1) ----
#pragma unroll
    for (int j = 0; j < 8; ++j) acc[j] = c[j];

    float* ob = out + (size_t)(b * T_) * D_ + (size_t)i * 8;
#pragma unroll 4
    for (int k = 0; k < CHUNK; ++k) {
        int t = t0 + k;
        int r1 = sidx[t - lo];
        unsigned ub1 = g_P1[r1 * ROWB + i];
        unsigned n8 = 0; float magp = 1.0f, magn = -0.4f;
        if (t >= 2) {
            int r2 = sidx[t - 1 - lo], r3 = sidx[t - 2 - lo];
            n8 = (unsigned)(g_P2[r2 * ROWB + i] ^ g_P3[r3 * ROWB + i]);
        } else { magp = 0.3f; magn = 0.3f; }
        bind_step(ub1, n8, magp, magn, acc);

        float invn = sinv[k];
        float4* o = (float4*)(ob + (size_t)t * D_);
        o[0] = make_float4(acc[0]*invn, acc[1]*invn, acc[2]*invn, acc[3]*invn);
        o[1] = make_float4(acc[4]*invn, acc[5]*invn, acc[6]*invn, acc[7]*invn);
    }
}

extern "C" void kernel_launch(void* const* d_in, const int* in_sizes, int n_in,
                              void* d_out, int out_size, void* d_ws, size_t ws_size,
                              hipStream_t stream) {
    const float* cb  = (const float*)d_in[0];   // (256, 4096) fp32
    const int*   idx = (const int*)d_in[1];     // (8, 2048) int32
    float*       out = (float*)d_out;           // (8, 2048, 4096) fp32

    pack_kernel <<<dim3((VOCAB * ROWB) / 256), dim3(256), 0, stream>>>(cb);
    fused_kernel<<<dim3(NTILE), dim3(THREADS), 0, stream>>>(idx, out);
}

// Round 2
// 304.705 us; speedup vs baseline: 7.0260x; 7.0260x over previous
//
#include <hip/hip_runtime.h>

// HDCProcessor — three-pass formulation, no inter-block synchronization.
//   hdc[b,t,d] = s1*(0.7*s2*s3 + 0.3) in {±1.0, ∓0.4}; 0.3*s1 for t<2.
//   out[t] = U[t]*(1-DEC)/(1-DEC^{t+1}),  U[t] = DEC*U[t-1] + hdc[t].
// Pass A (states): per-chunk local scan end-states S -> g_S (8 MiB, L2/L3-hot).
// Pass B (emit): each block REDUNDANTLY folds its entering carry from g_S
// (c = sum_{p<ch} dch^{ch-1-p} S[p], loads independent -> pipelined), then
// runs the seeded scan + normalize + store. No carry kernel, no g_C, no
// cross-block handshakes (round-1 lookback was fence-bound at 2.1 ms).

#define VOCAB   256
#define D_      4096
#define T_      2048
#define B_      8
#define DEC     0.95f
#define CHUNK   32
#define NCH     (T_/CHUNK)        // 64
#define THREADS 128
#define DGRP    (D_/(THREADS*8))  // 4  (each thread owns 8 consecutive d's)
#define ROWB    (D_/8)            // 512 bytes per packed row

__device__ unsigned char g_P1[VOCAB*ROWB];
__device__ unsigned char g_P2[VOCAB*ROWB];  // signs shifted by 1 along D
__device__ unsigned char g_P3[VOCAB*ROWB];  // signs shifted by 2 along D
__device__ float g_invn[T_];                // (1-DEC)/(1-DEC^{t+1})
__device__ float g_S[B_*NCH*D_];            // local chunk end states (8 MiB)

__global__ __launch_bounds__(256) void pack_kernel(const float* __restrict__ cb) {
    int gid = blockIdx.x * 256 + threadIdx.x;     // 0 .. VOCAB*ROWB-1
    int r   = gid >> 9;
    int byt = gid & 511;
    const float* row = cb + r * D_;
    unsigned b1 = 0, b2 = 0, b3 = 0;
#pragma unroll
    for (int j = 0; j < 8; ++j) {
        int d = byt * 8 + j;
        unsigned s1 = __float_as_uint(row[d]) >> 31;
        unsigned s2 = __float_as_uint(row[(d - 1) & (D_ - 1)]) >> 31;
        unsigned s3 = __float_as_uint(row[(d - 2) & (D_ - 1)]) >> 31;
        b1 |= s1 << j; b2 |= s2 << j; b3 |= s3 << j;
    }
    g_P1[gid] = (unsigned char)b1;
    g_P2[gid] = (unsigned char)b2;
    g_P3[gid] = (unsigned char)b3;
    if (gid < T_)
        g_invn[gid] = (1.0f - DEC) / (1.0f - powf(DEC, (float)(gid + 1)));
}

// Per-(b,d)-step bind value: v = ±1.0 or ∓0.4 (or 0.3*s1 for t<2).
__device__ __forceinline__ void bind_step(unsigned ub1, unsigned n8,
                                          float magp, float magn, float* acc) {
#pragma unroll
    for (int j = 0; j < 8; ++j) {
        float mag    = ((n8 >> j) & 1u) ? magn : magp;
        unsigned sgn = (ub1 << (31 - j)) & 0x80000000u;
        float v      = __uint_as_float(__float_as_uint(mag) ^ sgn);
        acc[j] = fmaf(acc[j], DEC, v);
    }
}

__global__ __launch_bounds__(THREADS) void states_kernel(const int* __restrict__ idx) {
    const int b  = blockIdx.z;
    const int ch = blockIdx.y;
    const int dg = blockIdx.x;
    const int t0 = ch * CHUNK;
    const int lo = (t0 - 2 > 0) ? (t0 - 2) : 0;

    __shared__ int sidx[CHUNK + 2];
    if (threadIdx.x < (unsigned)(t0 + CHUNK - lo))
        sidx[threadIdx.x] = idx[b * T_ + lo + threadIdx.x];
    __syncthreads();

    const int i = dg * THREADS + threadIdx.x;
    float acc[8];
#pragma unroll
    for (int j = 0; j < 8; ++j) acc[j] = 0.0f;

#pragma unroll 4
    for (int k = 0; k < CHUNK; ++k) {
        int t = t0 + k;
        int r1 = sidx[t - lo];
        unsigned ub1 = g_P1[r1 * ROWB + i];
        unsigned n8 = 0; float magp = 1.0f, magn = -0.4f;
        if (t >= 2) {
            int r2 = sidx[t - 1 - lo], r3 = sidx[t - 2 - lo];
            n8 = (unsigned)(g_P2[r2 * ROWB + i] ^ g_P3[r3 * ROWB + i]);
        } else { magp = 0.3f; magn = 0.3f; }
        bind_step(ub1, n8, magp, magn, acc);
    }

    float* S = g_S + (size_t)(b * NCH + ch) * D_ + (size_t)i * 8;
    ((float4*)S)[0] = make_float4(acc[0], acc[1], acc[2], acc[3]);
    ((float4*)S)[1] = make_float4(acc[4], acc[5], acc[6], acc[7]);
}

__global__ __launch_bounds__(THREADS) void emit_kernel(const int* __restrict__ idx,
                                                       float* __restrict__ out) {
    const int b  = blockIdx.z;
    const int ch = blockIdx.y;
    const int dg = blockIdx.x;
    const int t0 = ch * CHUNK;
    const int lo = (t0 - 2 > 0) ? (t0 - 2) : 0;

    __shared__ int   sidx[CHUNK + 2];
    __shared__ float sinv[CHUNK];
    if (threadIdx.x < (unsigned)(t0 + CHUNK - lo))
        sidx[threadIdx.x] = idx[b * T_ + lo + threadIdx.x];
    if (threadIdx.x < CHUNK)
        sinv[threadIdx.x] = g_invn[t0 + threadIdx.x];
    __syncthreads();

    const int i = dg * THREADS + threadIdx.x;

    // ---- entering carry: redundant fold over predecessor aggregates ----
    // c = sum_{p=0}^{ch-1} dch^{ch-1-p} * S[b,p,dslice]   (dch = DEC^CHUNK)
    float dch = DEC * DEC;            // DEC^32 by repeated squaring
    dch *= dch; dch *= dch; dch *= dch; dch *= dch;

    float c[8];
#pragma unroll
    for (int j = 0; j < 8; ++j) c[j] = 0.0f;
    {
        float w = 1.0f;
#pragma unroll 4
        for (int p = ch - 1; p >= 0; --p) {
            const float4* src = (const float4*)(g_S + (size_t)(b * NCH + p) * D_
                                                + (size_t)i * 8);
            float4 a0 = src[0];
            float4 a1 = src[1];
            c[0] = fmaf(w, a0.x, c[0]); c[1] = fmaf(w, a0.y, c[1]);
            c[2] = fmaf(w, a0.z, c[2]); c[3] = fmaf(w, a0.w, c[3]);
            c[4] = fmaf(w, a1.x, c[4]); c[5] = fmaf(w, a1.y, c[5]);
            c[6] = fmaf(w, a1.z, c[6]); c[7] = fmaf(w, a1.w, c[7]);
            w *= dch;
        }
    }

    // ---- seeded scan + normalize + store ----
    float acc[8];
#pragma unroll
    for (int j = 0; j < 8; ++j) acc[j] = c[j];

    float* ob = out + (size_t)(b * T_) * D_ + (size_t)i * 8;
#pragma unroll 4
    for (int k = 0; k < CHUNK; ++k) {
        int t = t0 + k;
        int r1 = sidx[t - lo];
        unsigned ub1 = g_P1[r1 * ROWB + i];
        unsigned n8 = 0; float magp = 1.0f, magn = -0.4f;
        if (t >= 2) {
            int r2 = sidx[t - 1 - lo], r3 = sidx[t - 2 - lo];
            n8 = (unsigned)(g_P2[r2 * ROWB + i] ^ g_P3[r3 * ROWB + i]);
        } else { magp = 0.3f; magn = 0.3f; }
        bind_step(ub1, n8, magp, magn, acc);

        float invn = sinv[k];
        float4* o = (float4*)(ob + (size_t)t * D_);
        o[0] = make_float4(acc[0]*invn, acc[1]*invn, acc[2]*invn, acc[3]*invn);
        o[1] = make_float4(acc[4]*invn, acc[5]*invn, acc[6]*invn, acc[7]*invn);
    }
}

extern "C" void kernel_launch(void* const* d_in, const int* in_sizes, int n_in,
                              void* d_out, int out_size, void* d_ws, size_t ws_size,
                              hipStream_t stream) {
    const float* cb  = (const float*)d_in[0];   // (256, 4096) fp32
    const int*   idx = (const int*)d_in[1];     // (8, 2048) int32
    float*       out = (float*)d_out;           // (8, 2048, 4096) fp32

    pack_kernel  <<<dim3((VOCAB * ROWB) / 256), dim3(256), 0, stream>>>(cb);
    states_kernel<<<dim3(DGRP, NCH, B_), dim3(THREADS), 0, stream>>>(idx);
    emit_kernel  <<<dim3(DGRP, NCH, B_), dim3(THREADS), 0, stream>>>(idx, out);
}